// Round 2
// baseline (377.772 us; speedup 1.0000x reference)
//
#include <hip/hip_runtime.h>
#include <hip/hip_bf16.h>
#include <stdint.h>

// GRUModel: y[t,b,:] = GRUCell(x[t,b,:], hid[t,b,:]) independently per (t,b).
// Inputs/outputs are fp32 (per reference); internal compute bf16 MFMA + fp32 acc.
// gi = x @ W_ih^T + b_ih, gh = hid @ W_hh^T + b_hh, M = T*B = 131072, N = 3H = 384, K = 128.
// Outputs: [y (M*128), hid copy (M*128)] fp32.

typedef __attribute__((ext_vector_type(8))) short short8;   // 8 bf16 = 4 VGPRs
typedef __attribute__((ext_vector_type(4))) float f32x4;

#define BM 64      // rows per block-tile
#define HT 32      // h-columns per block
#define RLOOP 4    // row-tiles per block

__device__ __forceinline__ float fast_sigmoid(float v) {
    return 1.0f / (1.0f + __expf(-v));
}
__device__ __forceinline__ float fast_tanh(float v) {
    // tanh(v) = 2*sigmoid(2v) - 1 ; inf-safe
    return 2.0f / (1.0f + __expf(-2.0f * v)) - 1.0f;
}

// fp32 -> bf16 (RNE), finite inputs only
__device__ __forceinline__ short f2bf(float f) {
    union { float f; uint32_t u; } v; v.f = f;
    uint32_t u = v.u + 0x7fffu + ((v.u >> 16) & 1u);
    return (short)(u >> 16);
}

__device__ __forceinline__ short8 pack8(f32x4 a, f32x4 b) {
    short8 r;
    r[0] = f2bf(a[0]); r[1] = f2bf(a[1]); r[2] = f2bf(a[2]); r[3] = f2bf(a[3]);
    r[4] = f2bf(b[0]); r[5] = f2bf(b[1]); r[6] = f2bf(b[2]); r[7] = f2bf(b[3]);
    return r;
}

__global__ __launch_bounds__(256) void gru_kernel(
    const float* __restrict__ x,
    const float* __restrict__ hid,
    const float* __restrict__ Wih,
    const float* __restrict__ Whh,
    const float* __restrict__ bih,
    const float* __restrict__ bhh,
    float* __restrict__ y,
    float* __restrict__ hout)
{
    // Weights (bf16) in MFMA fragment order: chunk idx = (g*2+c)*4+s, 1KB each,
    // lane*16 bytes within. g = {i_r,i_z,i_n,h_r,h_z,h_n}; c = 16-col tile; s = 32-wide k step.
    __shared__ __align__(16) short ws[48 * 512];   // 48 KB

    const int tid  = threadIdx.x;
    const int lane = tid & 63;
    const int wv   = tid >> 6;       // wave 0..3
    const int l15  = lane & 15;
    const int q    = lane >> 4;      // quad 0..3

    const int hb  = blockIdx.x & 3;          // h-tile 0..3 (32 cols each)
    const int rg  = blockIdx.x >> 2;         // row group
    const int nrg = gridDim.x >> 2;          // number of row groups

    // ---- stage all weights once: fp32 global -> bf16 LDS, fragment order ----
    #pragma unroll
    for (int i = 0; i < 12; ++i) {
        int idx = wv * 12 + i;               // 48 chunks over 4 waves
        int s   = idx & 3;
        int gc  = idx >> 2;                  // g*2 + c
        int c   = gc & 1;
        int g   = gc >> 1;                   // 0..5
        const float* Wp = (g < 3) ? Wih : Whh;
        int grow = (g % 3) * 128 + hb * HT + c * 16 + l15;
        int k    = s * 32 + q * 8;
        const float* src = Wp + (size_t)grow * 128 + k;
        f32x4 a = *(const f32x4*)src;
        f32x4 b = *(const f32x4*)(src + 4);
        *(short8*)((char*)ws + idx * 1024 + lane * 16) = pack8(a, b);
    }
    __syncthreads();

    // ---- per-lane biases (hoisted) ----
    float bir[2], biz[2], bin_[2], bhr[2], bhz[2], bhn[2];
    #pragma unroll
    for (int c = 0; c < 2; ++c) {
        int h = hb * HT + c * 16 + l15;
        bir[c]  = bih[h];
        biz[c]  = bih[128 + h];
        bin_[c] = bih[256 + h];
        bhr[c]  = bhh[h];
        bhz[c]  = bhh[128 + h];
        bhn[c]  = bhh[256 + h];
    }

    for (int j = 0; j < RLOOP; ++j) {
        const int  rb      = rg + j * nrg;          // row-tile id
        const long rowbase = (long)rb * BM;

        // second output: hid copy (hb==0 blocks, 16B vectorized)
        if (hb == 0) {
            const int4* src = (const int4*)(hid + rowbase * 128);
            int4*       dst = (int4*)(hout + rowbase * 128);
            #pragma unroll
            for (int i = 0; i < 8; ++i)
                dst[tid + 256 * i] = src[tid + 256 * i];
        }

        // ---- A fragments: fp32 global -> VGPR -> bf16 ----
        const float* xrow = x   + (rowbase + wv * 16 + l15) * 128 + q * 8;
        const float* hrow = hid + (rowbase + wv * 16 + l15) * 128 + q * 8;
        short8 xa[4], ha[4];
        #pragma unroll
        for (int s = 0; s < 4; ++s) {
            f32x4 a0 = *(const f32x4*)(xrow + s * 32);
            f32x4 a1 = *(const f32x4*)(xrow + s * 32 + 4);
            f32x4 b0 = *(const f32x4*)(hrow + s * 32);
            f32x4 b1 = *(const f32x4*)(hrow + s * 32 + 4);
            xa[s] = pack8(a0, a1);
            ha[s] = pack8(b0, b1);
        }

        f32x4 acc[2][6];
        #pragma unroll
        for (int c = 0; c < 2; ++c)
            #pragma unroll
            for (int g = 0; g < 6; ++g)
                acc[c][g] = (f32x4){0.f, 0.f, 0.f, 0.f};

        // ---- K loop: 4 steps of 32; 12 MFMAs per step ----
        #pragma unroll
        for (int s = 0; s < 4; ++s) {
            #pragma unroll
            for (int c = 0; c < 2; ++c) {
                #pragma unroll
                for (int g = 0; g < 6; ++g) {
                    int idx = (g * 2 + c) * 4 + s;
                    short8 b = *(const short8*)((const char*)ws + idx * 1024 + lane * 16);
                    acc[c][g] = __builtin_amdgcn_mfma_f32_16x16x32_bf16(
                        (g < 3) ? xa[s] : ha[s], b, acc[c][g], 0, 0, 0);
                }
            }
        }

        // ---- epilogue: gate math (C/D layout: col=lane&15, row=q*4+reg) ----
        #pragma unroll
        for (int c = 0; c < 2; ++c) {
            int hcol = hb * HT + c * 16 + l15;
            #pragma unroll
            for (int r = 0; r < 4; ++r) {
                long row = rowbase + wv * 16 + q * 4 + r;
                float ir_ = acc[c][0][r] + bir[c];
                float iz_ = acc[c][1][r] + biz[c];
                float in2 = acc[c][2][r] + bin_[c];
                float hr_ = acc[c][3][r] + bhr[c];
                float hz_ = acc[c][4][r] + bhz[c];
                float hn_ = acc[c][5][r] + bhn[c];
                float rr = fast_sigmoid(ir_ + hr_);
                float zz = fast_sigmoid(iz_ + hz_);
                float nn = fast_tanh(in2 + rr * hn_);
                float hv = hid[row * 128 + hcol];
                float yy = (1.0f - zz) * nn + zz * hv;
                y[row * 128 + hcol] = yy;
            }
        }
    }
}

extern "C" void kernel_launch(void* const* d_in, const int* in_sizes, int n_in,
                              void* d_out, int out_size, void* d_ws, size_t ws_size,
                              hipStream_t stream) {
    const float* x   = (const float*)d_in[0];
    const float* hid = (const float*)d_in[1];
    const float* Wih = (const float*)d_in[2];
    const float* Whh = (const float*)d_in[3];
    const float* bih = (const float*)d_in[4];
    const float* bhh = (const float*)d_in[5];

    const int M = in_sizes[0] / 128;               // T*B = 131072
    float* y    = (float*)d_out;
    float* hout = y + (size_t)M * 128;

    const int rowtiles = M / BM;                   // 2048
    const int grid     = (rowtiles / RLOOP) * 4;   // 2048 blocks (x4 h-tiles)

    gru_kernel<<<grid, 256, 0, stream>>>(x, hid, Wih, Whh, bih, bhh, y, hout);
}